// Round 5
// baseline (1426.049 us; speedup 1.0000x reference)
//
#include <hip/hip_runtime.h>
#include <hip/hip_bf16.h>
#include <math.h>

#define B_DIM 512
#define E_DIM 512
#define W_DIM 64
#define V_DIM 32000
#define H_DIM 5120

typedef short bf16x8 __attribute__((ext_vector_type(8)));
typedef float f32x4 __attribute__((ext_vector_type(4)));

// RNE f32->bf16 pair pack; compiler emits v_cvt_pk_bf16_f32 on gfx950.
static __device__ __forceinline__ unsigned pk2(float a, float b) {
  union { __hip_bfloat16 h; unsigned short u; } ca, cb;
  ca.h = __float2bfloat16(a);
  cb.h = __float2bfloat16(b);
  return (unsigned)ca.u | ((unsigned)cb.u << 16);
}

// ---------------- Attention: one block per batch row ----------------
__global__ __launch_bounds__(256) void attn_kernel(
    const float* __restrict__ state, const float* __restrict__ encode,
    const float* __restrict__ aW1, const float* __restrict__ aW2,
    const float* __restrict__ aW3, float* __restrict__ ctx) {
  const int b = blockIdx.x;
  const int tid = threadIdx.x;
  __shared__ float rq[512];
  __shared__ float sc[64];
  rq[tid]       = state[(size_t)b * 512 + tid]       * aW1[tid];
  rq[tid + 256] = state[(size_t)b * 512 + tid + 256] * aW1[tid + 256];
  __syncthreads();
  const int lane = tid & 63, wv = tid >> 6;
  const float* enc = encode + (size_t)b * 64 * 512;
  for (int w = wv; w < 64; w += 4) {
    const float* er  = enc + w * 512;
    const float* w2r = aW2 + w * 512;
    const float* w3r = aW3 + w * 512;
    float s = 0.f;
#pragma unroll
    for (int k = 0; k < 8; ++k) {
      int e = lane + k * 64;
      s += tanhf(rq[e] * er[e] * w2r[e]) * w3r[e];
    }
#pragma unroll
    for (int o = 32; o; o >>= 1) s += __shfl_xor(s, o, 64);
    if (lane == 0) sc[w] = s;
  }
  __syncthreads();
  if (tid < 64) {
    float v = sc[tid];
    float mx = v;
#pragma unroll
    for (int o = 32; o; o >>= 1) mx = fmaxf(mx, __shfl_xor(mx, o, 64));
    float e = __expf(v - mx);
    float sm = e;
#pragma unroll
    for (int o = 32; o; o >>= 1) sm += __shfl_xor(sm, o, 64);
    sc[tid] = e / sm;
  }
  __syncthreads();
  for (int e = tid; e < 512; e += 256) {
    float acc = 0.f;
#pragma unroll 8
    for (int w = 0; w < 64; ++w) acc += sc[w] * enc[w * 512 + e];
    ctx[(size_t)b * 512 + e] = acc;
  }
}

// ---------------- pack three [512,512] sources ----------------
__global__ __launch_bounds__(256) void pack3(
    const float* __restrict__ s0, const float* __restrict__ s1,
    const float* __restrict__ s2, float* __restrict__ dst, int mode) {
  const int s = blockIdx.y;
  const int i = blockIdx.x * 256 + threadIdx.x;
  const float* src = (s == 0) ? s0 : ((s == 1) ? s1 : s2);
  const float v = src[i];
  if (mode == 0) {
    dst[(size_t)s * 262144 + i] = v;
  } else {
    const int b = i >> 9, e = i & 511;
    dst[(size_t)b * 1536 + s * 512 + e] = v;
  }
}

// ---------------- GRU gate math ----------------
__global__ __launch_bounds__(256) void gru_gate(
    const float* __restrict__ X, const float* __restrict__ R, int rstride,
    const float* __restrict__ hprev, float* __restrict__ hout) {
  const int i = blockIdx.x * 256 + threadIdx.x;  // 0..262143
  const int b = i >> 9, e = i & 511;
  const float* Xr = X + (size_t)b * 1536;
  const float* Rr = R + (size_t)b * rstride;
  const float xz = Xr[e], xr = Xr[512 + e], xh = Xr[1024 + e];
  const float rz = Rr[e], rr = Rr[512 + e], rh = Rr[1024 + e];
  const float h = hprev ? hprev[i] : 0.f;
  const float z = 1.f / (1.f + __expf(-(xz + rz)));
  const float r = 1.f / (1.f + __expf(-(xr + rr)));
  const float hh = tanhf(xh + r * rh);
  hout[i] = z * h + (1.f - z) * hh;
}

// ---------------- bf16 MFMA GEMM: C = act(A@B + bias) ----------------
// A: [M,K] f32 row-major, B: [K,N] f32 row-major, C: [M,N] f32.
// M%128==0, N%128==0, K/PARTS % 64 == 0.  BK=64, single LDS buffer,
// B-loads hoisted one full iteration (depth-8 HBM prefetch in regs).
// LDS stride 72 shorts (144B). B^T writes chunk-XOR swizzled:
// uint4 for k-chunk q of col n lives at 16B-slot (q ^ ((n>>2)&3));
// write instrs land 8 lanes/16B-slot (conflict-free), frag reads balanced.
// PARTS>1: partial f32 to C + blockIdx.y*M*N, no bias/act.
template <int ACT, int PARTS, int SWZ>
__global__ __launch_bounds__(256, 2) void gemm_k(
    const float* __restrict__ A, const float* __restrict__ B,
    const float* __restrict__ bias, float* __restrict__ C,
    int M, int N, int K) {
  __shared__ unsigned short As[128 * 72];
  __shared__ unsigned short Bs[128 * 72];
  const int tid = threadIdx.x;
  int bid = blockIdx.x;
  if (SWZ) {
    const int q = gridDim.x >> 3;
    bid = (bid & 7) * q + (bid >> 3);
  }
  const int tiles_m = M >> 7;
  const int mt = bid % tiles_m;
  const int nt = bid / tiles_m;
  const long m0 = (long)mt * 128, n0 = (long)nt * 128;
  const int Kp = K / PARTS;
  const int k0 = blockIdx.y * Kp;

  // A staging: one m-row per thread, 32-k half
  const int a_m = tid & 127;
  const int a_h = tid >> 7;
  unsigned short* awp = As + a_m * 72 + a_h * 32;
  // B staging: 4 n-cols, 8 k-rows per thread
  const int b_n = (tid & 31) << 2;
  const int b_q = (tid >> 5) & 3;
  const int b_h = tid >> 7;
  const int b_sw = ((b_q ^ (tid & 3)) << 3) + b_h * 32;  // swizzled uint4 slot

  const int lane = tid & 63;
  const int wid = tid >> 6;
  const int wm = (wid >> 1) << 6, wn = (wid & 1) << 6;
  const int lr = lane & 15, lg = lane >> 4;

  int aro[4], bro[4];
#pragma unroll
  for (int i = 0; i < 4; ++i)
    aro[i] = (wm + 16 * i + lr) * 72 + 8 * lg;
#pragma unroll
  for (int j = 0; j < 4; ++j) {
    const int n = wn + 16 * j + lr;
    bro[j] = n * 72 + 8 * (lg ^ ((n >> 2) & 3));
  }

  f32x4 acc[4][4];
#pragma unroll
  for (int i = 0; i < 4; ++i)
#pragma unroll
    for (int j = 0; j < 4; ++j) acc[i][j] = f32x4{0.f, 0.f, 0.f, 0.f};

  const float* ap = A + (m0 + a_m) * (long)K + k0 + a_h * 32;
  const float* bp = B + (size_t)(k0 + b_h * 32 + b_q * 8) * N + n0 + b_n;

  // prologue: B tile 0 in flight
  float4 pb[8];
#pragma unroll
  for (int j = 0; j < 8; ++j) pb[j] = *(const float4*)(bp + (size_t)j * N);
  bp += (size_t)64 * N;

  const int nsteps = Kp >> 6;
  for (int t = 0; t < nsteps; ++t) {
    // A loads for tile t (small, L2-hot)
    float4 pa[8];
#pragma unroll
    for (int j = 0; j < 8; ++j) pa[j] = *(const float4*)(ap + 4 * j);
    ap += 64;
    // B cvt+write (regs issued a full iteration ago)
    {
      uint4 w;
      w.x = pk2(pb[0].x, pb[1].x); w.y = pk2(pb[2].x, pb[3].x);
      w.z = pk2(pb[4].x, pb[5].x); w.w = pk2(pb[6].x, pb[7].x);
      *(uint4*)(Bs + (b_n + 0) * 72 + b_sw) = w;
      w.x = pk2(pb[0].y, pb[1].y); w.y = pk2(pb[2].y, pb[3].y);
      w.z = pk2(pb[4].y, pb[5].y); w.w = pk2(pb[6].y, pb[7].y);
      *(uint4*)(Bs + (b_n + 1) * 72 + b_sw) = w;
      w.x = pk2(pb[0].z, pb[1].z); w.y = pk2(pb[2].z, pb[3].z);
      w.z = pk2(pb[4].z, pb[5].z); w.w = pk2(pb[6].z, pb[7].z);
      *(uint4*)(Bs + (b_n + 2) * 72 + b_sw) = w;
      w.x = pk2(pb[0].w, pb[1].w); w.y = pk2(pb[2].w, pb[3].w);
      w.z = pk2(pb[4].w, pb[5].w); w.w = pk2(pb[6].w, pb[7].w);
      *(uint4*)(Bs + (b_n + 3) * 72 + b_sw) = w;
    }
    // A cvt+write (linear, conflict-free)
#pragma unroll
    for (int c = 0; c < 4; ++c) {
      uint4 w;
      w.x = pk2(pa[2 * c].x, pa[2 * c].y);
      w.y = pk2(pa[2 * c].z, pa[2 * c].w);
      w.z = pk2(pa[2 * c + 1].x, pa[2 * c + 1].y);
      w.w = pk2(pa[2 * c + 1].z, pa[2 * c + 1].w);
      *(uint4*)(awp + 8 * c) = w;
    }
    __syncthreads();
    // issue B loads for t+1; they ride under ds_read+MFMA+barrier
    if (t + 1 < nsteps) {
#pragma unroll
      for (int j = 0; j < 8; ++j) pb[j] = *(const float4*)(bp + (size_t)j * N);
      bp += (size_t)64 * N;
    }
    // two 32-k subtiles
#pragma unroll
    for (int s = 0; s < 2; ++s) {
      bf16x8 af[4], bfr[4];
#pragma unroll
      for (int i = 0; i < 4; ++i)
        af[i] = *(const bf16x8*)(As + aro[i] + 32 * s);
#pragma unroll
      for (int j = 0; j < 4; ++j)
        bfr[j] = *(const bf16x8*)(Bs + bro[j] + 32 * s);
#pragma unroll
      for (int i = 0; i < 4; ++i)
#pragma unroll
        for (int j = 0; j < 4; ++j)
          acc[i][j] = __builtin_amdgcn_mfma_f32_16x16x32_bf16(af[i], bfr[j], acc[i][j], 0, 0, 0);
    }
    __syncthreads();
  }
  // epilogue
  float* Cp = (PARTS > 1) ? (C + (size_t)blockIdx.y * M * (size_t)N) : C;
#pragma unroll
  for (int j = 0; j < 4; ++j) {
    const long col = n0 + wn + j * 16 + lr;
    const float bv = (PARTS == 1 && bias) ? bias[col] : 0.f;
#pragma unroll
    for (int i = 0; i < 4; ++i) {
      const long row = m0 + wm + i * 16 + (lg << 2);
#pragma unroll
      for (int r = 0; r < 4; ++r) {
        float x = acc[i][j][r] + bv;
        if (PARTS == 1 && ACT == 1) x = tanhf(x);
        Cp[(row + r) * N + col] = x;
      }
    }
  }
}

// ---------------- split-K reduce: dst = act(sum_p P[p] + bias) ----------------
template <int ACT, int PARTS>
__global__ __launch_bounds__(256) void reduce_parts(
    const float* __restrict__ P, const float* __restrict__ bias,
    float* __restrict__ dst, int N) {
  const int col = blockIdx.x * 256 + threadIdx.x;
  const int row = blockIdx.y;
  const size_t MN = (size_t)gridDim.y * N;
  const size_t idx = (size_t)row * N + col;
  float s = bias[col];
#pragma unroll
  for (int p = 0; p < PARTS; ++p) s += P[p * MN + idx];
  dst[idx] = (ACT == 1) ? tanhf(s) : s;
}

// ---------------- row softmax, in place, [512, 32000] ----------------
__global__ __launch_bounds__(256) void softmax_rows(float* __restrict__ x) {
  const int b = blockIdx.x;
  float* row = x + (size_t)b * V_DIM;
  const int tid = threadIdx.x;
  __shared__ float red[4];
  const float4* r4 = (const float4*)row;
  float mx = -3.4e38f;
  for (int i = tid; i < V_DIM / 4; i += 256) {
    float4 v = r4[i];
    mx = fmaxf(mx, fmaxf(fmaxf(v.x, v.y), fmaxf(v.z, v.w)));
  }
#pragma unroll
  for (int o = 32; o; o >>= 1) mx = fmaxf(mx, __shfl_xor(mx, o, 64));
  if ((tid & 63) == 0) red[tid >> 6] = mx;
  __syncthreads();
  mx = fmaxf(fmaxf(red[0], red[1]), fmaxf(red[2], red[3]));
  __syncthreads();
  float s = 0.f;
  for (int i = tid; i < V_DIM / 4; i += 256) {
    float4 v = r4[i];
    s += __expf(v.x - mx) + __expf(v.y - mx) + __expf(v.z - mx) + __expf(v.w - mx);
  }
#pragma unroll
  for (int o = 32; o; o >>= 1) s += __shfl_xor(s, o, 64);
  if ((tid & 63) == 0) red[tid >> 6] = s;
  __syncthreads();
  s = red[0] + red[1] + red[2] + red[3];
  const float inv = 1.f / s;
  float4* w4p = (float4*)row;
  for (int i = tid; i < V_DIM / 4; i += 256) {
    float4 v = r4[i];
    float4 o4;
    o4.x = __expf(v.x - mx) * inv;
    o4.y = __expf(v.y - mx) * inv;
    o4.z = __expf(v.z - mx) * inv;
    o4.w = __expf(v.w - mx) * inv;
    w4p[i] = o4;
  }
}

extern "C" void kernel_launch(void* const* d_in, const int* in_sizes, int n_in,
                              void* d_out, int out_size, void* d_ws, size_t ws_size,
                              hipStream_t stream) {
  const float* y      = (const float*)d_in[0];
  const float* state  = (const float*)d_in[1];
  const float* encode = (const float*)d_in[2];
  const float* aW1    = (const float*)d_in[3];
  const float* aW2    = (const float*)d_in[4];
  const float* aW3    = (const float*)d_in[5];
  const float* gk     = (const float*)d_in[6];
  const float* grk    = (const float*)d_in[7];
  const float* gb     = (const float*)d_in[8];
  const float* w1     = (const float*)d_in[9];
  const float* b1     = (const float*)d_in[10];
  const float* w2     = (const float*)d_in[11];
  const float* b2     = (const float*)d_in[12];
  const float* w3     = (const float*)d_in[13];
  const float* b3     = (const float*)d_in[14];
  float* out = (float*)d_out;
  float* ws = (float*)d_ws;

  float* ctx = ws;                 // 262144
  float* seq = ws + 262144;        // 786432  rows: t*512+b
  float* X   = ws + 1048576;       // 2359296 rows: t*512+b, cols 1536
  float* R   = ws + 3407872;       // 786432
  float* hg1 = ws + 4194304;       // 262144
  float* hg2 = ws + 4456448;       // 262144
  float* g   = ws + 4718592;       // 786432
  float* dd1 = ws + 5505024;       // 2621440
  float* dd2 = ws + 8126464;       // 2621440

  float* g_out = out;                               // [512, 32000]
  float* h3 = out + (size_t)B_DIM * V_DIM;          // new_state [512, 512]
  // split-K partials parked in the (not yet written) logits region of d_out:
  // max 4 parts * 512*5120 f32 = 10.49M floats < 16.38M logits floats.
  float* P = out;

  const float* bi = gb;
  const float* br = gb + 1536;

  attn_kernel<<<512, 256, 0, stream>>>(state, encode, aW1, aW2, aW3, ctx);
  pack3<<<dim3(1024, 3), 256, 0, stream>>>(state, ctx, y, seq, 0);
  // Xall = seq @ gk + bi : [1536,1536] = [1536,512]@[512,1536]
  gemm_k<0, 1, 0><<<12 * 12, 256, 0, stream>>>(seq, gk, bi, X, 1536, 1536, 512);
  // GRU t=0 (h=0 -> R row = br)
  gru_gate<<<1024, 256, 0, stream>>>(X, br, 0, nullptr, hg1);
  // GRU t=1
  gemm_k<0, 1, 0><<<4 * 12, 256, 0, stream>>>(hg1, grk, br, R, 512, 1536, 512);
  gru_gate<<<1024, 256, 0, stream>>>(X + 786432, R, 1536, hg1, hg2);
  // GRU t=2 -> new_state straight into d_out tail
  gemm_k<0, 1, 0><<<4 * 12, 256, 0, stream>>>(hg2, grk, br, R, 512, 1536, 512);
  gru_gate<<<1024, 256, 0, stream>>>(X + 1572864, R, 1536, hg2, h3);
  // g = [y | ctx | new_state]
  pack3<<<dim3(1024, 3), 256, 0, stream>>>(y, ctx, h3, g, 1);
  // dense stack: h1 = tanh(g@w1+b1) via split-K=2
  gemm_k<0, 2, 0><<<dim3(4 * 40, 2), 256, 0, stream>>>(g, w1, b1, P, 512, H_DIM, 1536);
  reduce_parts<1, 2><<<dim3(20, 512), 256, 0, stream>>>(P, b1, dd1, H_DIM);
  // h2 = tanh(h1@w2+b2) via split-K=4
  gemm_k<0, 4, 0><<<dim3(4 * 40, 4), 256, 0, stream>>>(dd1, w2, b2, P, 512, H_DIM, H_DIM);
  reduce_parts<1, 4><<<dim3(20, 512), 256, 0, stream>>>(P, b2, dd2, H_DIM);
  // logits GEMM — within-round A/B: SWZ=1 first (cold-cache handicap), SWZ=0 second.
  gemm_k<0, 1, 1><<<4 * 250, 256, 0, stream>>>(dd2, w3, b3, g_out, 512, V_DIM, H_DIM);
  gemm_k<0, 1, 0><<<4 * 250, 256, 0, stream>>>(dd2, w3, b3, g_out, 512, V_DIM, H_DIM);
  softmax_rows<<<512, 256, 0, stream>>>(g_out);
}

// Round 6
// 761.797 us; speedup vs baseline: 1.8720x; 1.8720x over previous
//
#include <hip/hip_runtime.h>
#include <hip/hip_bf16.h>
#include <math.h>

#define B_DIM 512
#define E_DIM 512
#define W_DIM 64
#define V_DIM 32000
#define H_DIM 5120

typedef short bf16x8 __attribute__((ext_vector_type(8)));
typedef float f32x4 __attribute__((ext_vector_type(4)));

// RNE f32->bf16 pair pack; compiler emits v_cvt_pk_bf16_f32 on gfx950.
static __device__ __forceinline__ unsigned pk2(float a, float b) {
  union { __hip_bfloat16 h; unsigned short u; } ca, cb;
  ca.h = __float2bfloat16(a);
  cb.h = __float2bfloat16(b);
  return (unsigned)ca.u | ((unsigned)cb.u << 16);
}
static __device__ __forceinline__ unsigned short f2b(float a) {
  union { __hip_bfloat16 h; unsigned short u; } c;
  c.h = __float2bfloat16(a);
  return c.u;
}

// ---------------- Attention: one block per batch row ----------------
__global__ __launch_bounds__(256) void attn_kernel(
    const float* __restrict__ state, const float* __restrict__ encode,
    const float* __restrict__ aW1, const float* __restrict__ aW2,
    const float* __restrict__ aW3, float* __restrict__ ctx) {
  const int b = blockIdx.x;
  const int tid = threadIdx.x;
  __shared__ float rq[512];
  __shared__ float sc[64];
  rq[tid]       = state[(size_t)b * 512 + tid]       * aW1[tid];
  rq[tid + 256] = state[(size_t)b * 512 + tid + 256] * aW1[tid + 256];
  __syncthreads();
  const int lane = tid & 63, wv = tid >> 6;
  const float* enc = encode + (size_t)b * 64 * 512;
  for (int w = wv; w < 64; w += 4) {
    const float* er  = enc + w * 512;
    const float* w2r = aW2 + w * 512;
    const float* w3r = aW3 + w * 512;
    float s = 0.f;
#pragma unroll
    for (int k = 0; k < 8; ++k) {
      int e = lane + k * 64;
      s += tanhf(rq[e] * er[e] * w2r[e]) * w3r[e];
    }
#pragma unroll
    for (int o = 32; o; o >>= 1) s += __shfl_xor(s, o, 64);
    if (lane == 0) sc[w] = s;
  }
  __syncthreads();
  if (tid < 64) {
    float v = sc[tid];
    float mx = v;
#pragma unroll
    for (int o = 32; o; o >>= 1) mx = fmaxf(mx, __shfl_xor(mx, o, 64));
    float e = __expf(v - mx);
    float sm = e;
#pragma unroll
    for (int o = 32; o; o >>= 1) sm += __shfl_xor(sm, o, 64);
    sc[tid] = e / sm;
  }
  __syncthreads();
  for (int e = tid; e < 512; e += 256) {
    float acc = 0.f;
#pragma unroll 8
    for (int w = 0; w < 64; ++w) acc += sc[w] * enc[w * 512 + e];
    ctx[(size_t)b * 512 + e] = acc;
  }
}

// ---------------- pack three [512,512] sources (f32 out, GRU stack) ----------------
__global__ __launch_bounds__(256) void pack3(
    const float* __restrict__ s0, const float* __restrict__ s1,
    const float* __restrict__ s2, float* __restrict__ dst) {
  const int s = blockIdx.y;
  const int i = blockIdx.x * 256 + threadIdx.x;
  const float* src = (s == 0) ? s0 : ((s == 1) ? s1 : s2);
  dst[(size_t)s * 262144 + i] = src[i];
}

// ---------------- pack three -> bf16 concat [512][1536] ----------------
__global__ __launch_bounds__(256) void pack3b(
    const float* __restrict__ s0, const float* __restrict__ s1,
    const float* __restrict__ s2, unsigned short* __restrict__ dst) {
  const int s = blockIdx.y;
  const int i = blockIdx.x * 256 + threadIdx.x;
  const float* src = (s == 0) ? s0 : ((s == 1) ? s1 : s2);
  const int b = i >> 9, e = i & 511;
  dst[(size_t)b * 1536 + s * 512 + e] = f2b(src[i]);
}

// ---------------- GRU gate math ----------------
__global__ __launch_bounds__(256) void gru_gate(
    const float* __restrict__ X, const float* __restrict__ R, int rstride,
    const float* __restrict__ hprev, float* __restrict__ hout) {
  const int i = blockIdx.x * 256 + threadIdx.x;  // 0..262143
  const int b = i >> 9, e = i & 511;
  const float* Xr = X + (size_t)b * 1536;
  const float* Rr = R + (size_t)b * rstride;
  const float xz = Xr[e], xr = Xr[512 + e], xh = Xr[1024 + e];
  const float rz = Rr[e], rr = Rr[512 + e], rh = Rr[1024 + e];
  const float h = hprev ? hprev[i] : 0.f;
  const float z = 1.f / (1.f + __expf(-(xz + rz)));
  const float r = 1.f / (1.f + __expf(-(xr + rr)));
  const float hh = tanhf(xh + r * rh);
  hout[i] = z * h + (1.f - z) * hh;
}

// ---------------- small-M bf16 MFMA GEMM (GRU path, A f32) ----------------
#define LSTR 40
template <int ACT>
__global__ __launch_bounds__(256, 2) void gemm_k(
    const float* __restrict__ A, const float* __restrict__ B,
    const float* __restrict__ bias, float* __restrict__ C,
    int M, int N, int K) {
  __shared__ unsigned short As[128 * 72];
  __shared__ unsigned short Bs[128 * 72];
  const int tid = threadIdx.x;
  const int bid = blockIdx.x;
  const int tiles_m = M >> 7;
  const int mt = bid % tiles_m;
  const int nt = bid / tiles_m;
  const long m0 = (long)mt * 128, n0 = (long)nt * 128;

  const int a_m = tid & 127;
  const int a_h = tid >> 7;
  unsigned short* awp = As + a_m * 72 + a_h * 32;
  const int b_n = (tid & 31) << 2;
  const int b_q = (tid >> 5) & 3;
  const int b_h = tid >> 7;
  const int b_sw = ((b_q ^ (tid & 3)) << 3) + b_h * 32;

  const int lane = tid & 63;
  const int wid = tid >> 6;
  const int wm = (wid >> 1) << 6, wn = (wid & 1) << 6;
  const int lr = lane & 15, lg = lane >> 4;

  int aro[4], bro[4];
#pragma unroll
  for (int i = 0; i < 4; ++i)
    aro[i] = (wm + 16 * i + lr) * 72 + 8 * lg;
#pragma unroll
  for (int j = 0; j < 4; ++j) {
    const int n = wn + 16 * j + lr;
    bro[j] = n * 72 + 8 * (lg ^ ((n >> 2) & 3));
  }

  f32x4 acc[4][4];
#pragma unroll
  for (int i = 0; i < 4; ++i)
#pragma unroll
    for (int j = 0; j < 4; ++j) acc[i][j] = f32x4{0.f, 0.f, 0.f, 0.f};

  const float* ap = A + (m0 + a_m) * (long)K + a_h * 32;
  const float* bp = B + (size_t)(b_h * 32 + b_q * 8) * N + n0 + b_n;

  float4 pb[8];
#pragma unroll
  for (int j = 0; j < 8; ++j) pb[j] = *(const float4*)(bp + (size_t)j * N);
  bp += (size_t)64 * N;

  const int nsteps = K >> 6;
  for (int t = 0; t < nsteps; ++t) {
    float4 pa[8];
#pragma unroll
    for (int j = 0; j < 8; ++j) pa[j] = *(const float4*)(ap + 4 * j);
    ap += 64;
    {
      uint4 w;
      w.x = pk2(pb[0].x, pb[1].x); w.y = pk2(pb[2].x, pb[3].x);
      w.z = pk2(pb[4].x, pb[5].x); w.w = pk2(pb[6].x, pb[7].x);
      *(uint4*)(Bs + (b_n + 0) * 72 + b_sw) = w;
      w.x = pk2(pb[0].y, pb[1].y); w.y = pk2(pb[2].y, pb[3].y);
      w.z = pk2(pb[4].y, pb[5].y); w.w = pk2(pb[6].y, pb[7].y);
      *(uint4*)(Bs + (b_n + 1) * 72 + b_sw) = w;
      w.x = pk2(pb[0].z, pb[1].z); w.y = pk2(pb[2].z, pb[3].z);
      w.z = pk2(pb[4].z, pb[5].z); w.w = pk2(pb[6].z, pb[7].z);
      *(uint4*)(Bs + (b_n + 2) * 72 + b_sw) = w;
      w.x = pk2(pb[0].w, pb[1].w); w.y = pk2(pb[2].w, pb[3].w);
      w.z = pk2(pb[4].w, pb[5].w); w.w = pk2(pb[6].w, pb[7].w);
      *(uint4*)(Bs + (b_n + 3) * 72 + b_sw) = w;
    }
#pragma unroll
    for (int c = 0; c < 4; ++c) {
      uint4 w;
      w.x = pk2(pa[2 * c].x, pa[2 * c].y);
      w.y = pk2(pa[2 * c].z, pa[2 * c].w);
      w.z = pk2(pa[2 * c + 1].x, pa[2 * c + 1].y);
      w.w = pk2(pa[2 * c + 1].z, pa[2 * c + 1].w);
      *(uint4*)(awp + 8 * c) = w;
    }
    __syncthreads();
    if (t + 1 < nsteps) {
#pragma unroll
      for (int j = 0; j < 8; ++j) pb[j] = *(const float4*)(bp + (size_t)j * N);
      bp += (size_t)64 * N;
    }
#pragma unroll
    for (int s = 0; s < 2; ++s) {
      bf16x8 af[4], bfr[4];
#pragma unroll
      for (int i = 0; i < 4; ++i)
        af[i] = *(const bf16x8*)(As + aro[i] + 32 * s);
#pragma unroll
      for (int j = 0; j < 4; ++j)
        bfr[j] = *(const bf16x8*)(Bs + bro[j] + 32 * s);
#pragma unroll
      for (int i = 0; i < 4; ++i)
#pragma unroll
        for (int j = 0; j < 4; ++j)
          acc[i][j] = __builtin_amdgcn_mfma_f32_16x16x32_bf16(af[i], bfr[j], acc[i][j], 0, 0, 0);
    }
    __syncthreads();
  }
#pragma unroll
  for (int j = 0; j < 4; ++j) {
    const long col = n0 + wn + j * 16 + lr;
    const float bv = bias ? bias[col] : 0.f;
#pragma unroll
    for (int i = 0; i < 4; ++i) {
      const long row = m0 + wm + i * 16 + (lg << 2);
#pragma unroll
      for (int r = 0; r < 4; ++r) {
        float x = acc[i][j][r] + bv;
        if (ACT == 1) x = tanhf(x);
        C[(row + r) * N + col] = x;
      }
    }
  }
}

// ---------------- full-M GEMM: C[512,N] = A16[512,K] @ B[K,N] ----------------
// A16 bf16 row-major (pre-converted). One block covers ALL 512 rows of a
// 128-col panel -> B read exactly once (structural reuse, not cache-luck).
// 8 waves (512 thr), wave tile 128x64, BK=64. LDS stride 72 shorts (144B):
// A linear slots (uniform bank floor), B 16B-slot XOR swizzle keyed (n>>3)&7.
// PARTS>1: k-sliced partials to C + by*512*N, no bias/act.
template <int ACT, int PARTS>
__global__ __launch_bounds__(512, 2) void gemm_fm(
    const unsigned short* __restrict__ A16, const float* __restrict__ B,
    const float* __restrict__ bias, float* __restrict__ C,
    int N, int K) {
  __shared__ unsigned short As[512 * 72];
  __shared__ unsigned short Bs[128 * 72];
  const int tid = threadIdx.x;
  const long n0 = (long)blockIdx.x * 128;
  const int Kp = K / PARTS;
  const int k0 = blockIdx.y * Kp;

  // A staging: thread covers rows a_r0+64j (j=0..7), 16B chunk a_c
  const int a_r0 = tid >> 3;
  const int a_c = tid & 7;
  // B staging: 4 cols b_n.., k-rows 4*b_g.., swizzled 8B granule b_gs
  const int b_x = tid & 31;
  const int b_n = b_x << 2;
  const int b_g = tid >> 5;  // 0..15
  const int b_gs = ((((b_g >> 1) ^ ((b_x >> 1) & 7)) << 1) | (b_g & 1));

  const int lane = tid & 63;
  const int wid = tid >> 6;
  const int wm = (wid >> 1) << 7;  // 0..384
  const int wn = (wid & 1) << 6;   // 0,64
  const int lr = lane & 15, lg = lane >> 4;

  int aro[8];
#pragma unroll
  for (int i = 0; i < 8; ++i) aro[i] = (wm + 16 * i + lr) * 72 + 8 * lg;
  int bbase[4], bslot[4];
#pragma unroll
  for (int j = 0; j < 4; ++j) {
    const int n = wn + 16 * j + lr;
    bbase[j] = n * 72;
    bslot[j] = lg ^ ((n >> 3) & 7);
  }

  f32x4 acc[8][4];
#pragma unroll
  for (int i = 0; i < 8; ++i)
#pragma unroll
    for (int j = 0; j < 4; ++j) acc[i][j] = f32x4{0.f, 0.f, 0.f, 0.f};

  const unsigned short* ap = A16 + (size_t)a_r0 * K + k0 + a_c * 8;
  const float* bp = B + (size_t)(k0 + b_g * 4) * N + n0 + b_n;

  uint4 pa[8];
  float4 pb[4];
#pragma unroll
  for (int j = 0; j < 8; ++j) pa[j] = *(const uint4*)(ap + (size_t)(64 * j) * K);
#pragma unroll
  for (int r = 0; r < 4; ++r) pb[r] = *(const float4*)(bp + (size_t)r * N);
  ap += 64;
  bp += (size_t)64 * N;

  const int nsteps = Kp >> 6;
  for (int t = 0; t < nsteps; ++t) {
    // LDS write from prefetched regs
#pragma unroll
    for (int j = 0; j < 8; ++j)
      *(uint4*)(As + (a_r0 + 64 * j) * 72 + a_c * 8) = pa[j];
    {
      uint2 qv;
      qv.x = pk2(pb[0].x, pb[1].x); qv.y = pk2(pb[2].x, pb[3].x);
      *(uint2*)(Bs + (b_n + 0) * 72 + b_gs * 4) = qv;
      qv.x = pk2(pb[0].y, pb[1].y); qv.y = pk2(pb[2].y, pb[3].y);
      *(uint2*)(Bs + (b_n + 1) * 72 + b_gs * 4) = qv;
      qv.x = pk2(pb[0].z, pb[1].z); qv.y = pk2(pb[2].z, pb[3].z);
      *(uint2*)(Bs + (b_n + 2) * 72 + b_gs * 4) = qv;
      qv.x = pk2(pb[0].w, pb[1].w); qv.y = pk2(pb[2].w, pb[3].w);
      *(uint2*)(Bs + (b_n + 3) * 72 + b_gs * 4) = qv;
    }
    __syncthreads();
    // issue next-tile loads; they fly under ds_read+MFMA
    if (t + 1 < nsteps) {
#pragma unroll
      for (int j = 0; j < 8; ++j) pa[j] = *(const uint4*)(ap + (size_t)(64 * j) * K);
#pragma unroll
      for (int r = 0; r < 4; ++r) pb[r] = *(const float4*)(bp + (size_t)r * N);
      ap += 64;
      bp += (size_t)64 * N;
    }
#pragma unroll
    for (int s = 0; s < 2; ++s) {
      bf16x8 af[8], bfr[4];
#pragma unroll
      for (int i = 0; i < 8; ++i)
        af[i] = *(const bf16x8*)(As + aro[i] + 32 * s);
#pragma unroll
      for (int j = 0; j < 4; ++j)
        bfr[j] = *(const bf16x8*)(Bs + bbase[j] + 8 * (bslot[j] ^ (s << 2)));
#pragma unroll
      for (int i = 0; i < 8; ++i)
#pragma unroll
        for (int j = 0; j < 4; ++j)
          acc[i][j] = __builtin_amdgcn_mfma_f32_16x16x32_bf16(af[i], bfr[j], acc[i][j], 0, 0, 0);
    }
    __syncthreads();
  }
  float* Cp = (PARTS > 1) ? (C + (size_t)blockIdx.y * 512 * (size_t)N) : C;
#pragma unroll
  for (int j = 0; j < 4; ++j) {
    const long col = n0 + wn + j * 16 + lr;
    const float bv = (PARTS == 1 && bias) ? bias[col] : 0.f;
#pragma unroll
    for (int i = 0; i < 8; ++i) {
      const long row = wm + i * 16 + (lg << 2);
#pragma unroll
      for (int r = 0; r < 4; ++r) {
        float x = acc[i][j][r] + bv;
        if (PARTS == 1 && ACT == 1) x = tanhf(x);
        Cp[(row + r) * N + col] = x;
      }
    }
  }
}

// ---------------- split-K reduce: dst = act(sum_p P[p] + bias), bf16 out ----------------
template <int ACT, int PARTS>
__global__ __launch_bounds__(256) void reduce_parts_b(
    const float* __restrict__ P, const float* __restrict__ bias,
    unsigned short* __restrict__ dst, int N) {
  const int col = blockIdx.x * 256 + threadIdx.x;
  const int row = blockIdx.y;
  const size_t MN = (size_t)gridDim.y * N;
  const size_t idx = (size_t)row * N + col;
  float s = bias[col];
#pragma unroll
  for (int p = 0; p < PARTS; ++p) s += P[p * MN + idx];
  dst[idx] = f2b((ACT == 1) ? tanhf(s) : s);
}

// ---------------- row softmax, in place, [512, 32000] ----------------
__global__ __launch_bounds__(256) void softmax_rows(float* __restrict__ x) {
  const int b = blockIdx.x;
  float* row = x + (size_t)b * V_DIM;
  const int tid = threadIdx.x;
  __shared__ float red[4];
  const float4* r4 = (const float4*)row;
  float mx = -3.4e38f;
  for (int i = tid; i < V_DIM / 4; i += 256) {
    float4 v = r4[i];
    mx = fmaxf(mx, fmaxf(fmaxf(v.x, v.y), fmaxf(v.z, v.w)));
  }
#pragma unroll
  for (int o = 32; o; o >>= 1) mx = fmaxf(mx, __shfl_xor(mx, o, 64));
  if ((tid & 63) == 0) red[tid >> 6] = mx;
  __syncthreads();
  mx = fmaxf(fmaxf(red[0], red[1]), fmaxf(red[2], red[3]));
  __syncthreads();
  float s = 0.f;
  for (int i = tid; i < V_DIM / 4; i += 256) {
    float4 v = r4[i];
    s += __expf(v.x - mx) + __expf(v.y - mx) + __expf(v.z - mx) + __expf(v.w - mx);
  }
#pragma unroll
  for (int o = 32; o; o >>= 1) s += __shfl_xor(s, o, 64);
  if ((tid & 63) == 0) red[tid >> 6] = s;
  __syncthreads();
  s = red[0] + red[1] + red[2] + red[3];
  const float inv = 1.f / s;
  float4* w4p = (float4*)row;
  for (int i = tid; i < V_DIM / 4; i += 256) {
    float4 v = r4[i];
    float4 o4;
    o4.x = __expf(v.x - mx) * inv;
    o4.y = __expf(v.y - mx) * inv;
    o4.z = __expf(v.z - mx) * inv;
    o4.w = __expf(v.w - mx) * inv;
    w4p[i] = o4;
  }
}

extern "C" void kernel_launch(void* const* d_in, const int* in_sizes, int n_in,
                              void* d_out, int out_size, void* d_ws, size_t ws_size,
                              hipStream_t stream) {
  const float* y      = (const float*)d_in[0];
  const float* state  = (const float*)d_in[1];
  const float* encode = (const float*)d_in[2];
  const float* aW1    = (const float*)d_in[3];
  const float* aW2    = (const float*)d_in[4];
  const float* aW3    = (const float*)d_in[5];
  const float* gk     = (const float*)d_in[6];
  const float* grk    = (const float*)d_in[7];
  const float* gb     = (const float*)d_in[8];
  const float* w1     = (const float*)d_in[9];
  const float* b1     = (const float*)d_in[10];
  const float* w2     = (const float*)d_in[11];
  const float* b2     = (const float*)d_in[12];
  const float* w3     = (const float*)d_in[13];
  const float* b3     = (const float*)d_in[14];
  float* out = (float*)d_out;
  float* ws = (float*)d_ws;

  float* ctx = ws;                          // 262144 f32
  float* seq = ws + 262144;                 // 786432 f32
  float* X   = ws + 1048576;                // 2359296 f32
  float* R   = ws + 3407872;                // 786432 f32
  float* hg1 = ws + 4194304;                // 262144 f32
  float* hg2 = ws + 4456448;                // 262144 f32
  unsigned short* gb16  = (unsigned short*)(ws + 4718592);  // 512*1536 bf16
  unsigned short* dd1b  = (unsigned short*)(ws + 5111808);  // 512*5120 bf16
  unsigned short* dd2b  = (unsigned short*)(ws + 6422528);  // 512*5120 bf16

  float* g_out = out;                               // [512, 32000]
  float* h3 = out + (size_t)B_DIM * V_DIM;          // new_state [512, 512]
  float* P = out;  // split-K partials in not-yet-written logits region
                   // (max 6 * 512*5120 f32 = 63 MB < 65.5 MB)

  const float* bi = gb;
  const float* br = gb + 1536;

  attn_kernel<<<512, 256, 0, stream>>>(state, encode, aW1, aW2, aW3, ctx);
  pack3<<<dim3(1024, 3), 256, 0, stream>>>(state, ctx, y, seq);
  // Xall = seq @ gk + bi : [1536,1536] = [1536,512]@[512,1536]
  gemm_k<0><<<12 * 12, 256, 0, stream>>>(seq, gk, bi, X, 1536, 1536, 512);
  gru_gate<<<1024, 256, 0, stream>>>(X, br, 0, nullptr, hg1);
  gemm_k<0><<<4 * 12, 256, 0, stream>>>(hg1, grk, br, R, 512, 1536, 512);
  gru_gate<<<1024, 256, 0, stream>>>(X + 786432, R, 1536, hg1, hg2);
  gemm_k<0><<<4 * 12, 256, 0, stream>>>(hg2, grk, br, R, 512, 1536, 512);
  gru_gate<<<1024, 256, 0, stream>>>(X + 1572864, R, 1536, hg2, h3);
  // g = [y | ctx | new_state] as bf16 (A-operand of w1 GEMM)
  pack3b<<<dim3(1024, 3), 256, 0, stream>>>(y, ctx, h3, gb16);
  // h1 = tanh(g@w1+b1): full-M, split-K=6 (K slice 256)
  gemm_fm<0, 6><<<dim3(40, 6), 512, 0, stream>>>(gb16, w1, nullptr, P, H_DIM, 1536);
  reduce_parts_b<1, 6><<<dim3(20, 512), 256, 0, stream>>>(P, b1, dd1b, H_DIM);
  // h2 = tanh(h1@w2+b2): full-M, split-K=5 (K slice 1024)
  gemm_fm<0, 5><<<dim3(40, 5), 512, 0, stream>>>(dd1b, w2, nullptr, P, H_DIM, H_DIM);
  reduce_parts_b<1, 5><<<dim3(20, 512), 256, 0, stream>>>(P, b2, dd2b, H_DIM);
  // logits = h2@w3+b3: full-M, one block per 128-col panel (B read once)
  gemm_fm<0, 1><<<dim3(250, 1), 512, 0, stream>>>(dd2b, w3, b3, g_out, V_DIM, H_DIM);
  softmax_rows<<<512, 256, 0, stream>>>(g_out);
}